// Round 3
// baseline (480.718 us; speedup 1.0000x reference)
//
#include <hip/hip_runtime.h>
#include <hip/hip_bf16.h>

typedef unsigned short ushort_t;

#define MAPC 250000
#define NCH 2048          // chunks for mask scan
#define CHSZ 1024         // pixels per chunk
#define NPOS 500000       // only slots < 500000 are ever referenced (proj < 500000)

// ws layout (bytes) — total 6,277,248
#define OFF_SCAL   0          // int[8]: [0]=max(proj) [1]=n_inliers [2]=f32mode [3]=projmode [4]=maskmode
#define OFF_CNT    1024       // int[2048] chunk counts -> exclusive prefix
#define OFF_POS    16384      // int[NPOS]  (2 MB)
#define OFF_FEATT  2016384    // bf16[128*256*64] (4 MB), layout [y][x][c]
#define OFF_WF     6210688    // float[256*64]
#define OFF_BF     6276224    // float[256]

__device__ inline int mask_at(const void* m, int mode, int px) {
    if (mode == 0) return ((const unsigned char*)m)[px] != 0;   // bool as u8
    if (mode == 2) return ((const ushort_t*)m)[px] != 0;        // bool as bf16
    return ((const int*)m)[px] != 0;                            // bool as i32 / f32
}

__device__ inline int proj_at(const int* p, int mode, int i) {
    return mode ? p[2 * i] : p[i];                              // int64 low word / int32
}

// Detect input layouts + convert W/b to f32. One block, 256 threads.
__global__ void k_detect(const void* feats, const int* pj, const void* mbv,
                         const void* Wv, const void* bv,
                         float* __restrict__ Wf, float* __restrict__ bf,
                         int* __restrict__ scal) {
    __shared__ int s_insane, s_oddnz, s_non01, s_off4, s_low2;
    int t = threadIdx.x;
    if (t == 0) { s_insane = 0; s_oddnz = 0; s_non01 = 0; s_off4 = 0; s_low2 = 0; }
    __syncthreads();
    // float-mode: even-index ushorts of features. bf16 buffer -> sane exponents;
    // fp32 buffer -> these are low mantissa bits -> ~84% insane.
    {
        ushort_t u = ((const ushort_t*)feats)[2 * t];
        int e = (u >> 7) & 0xFF;
        if (e < 0x66 || e > 0x8E) atomicAdd(&s_insane, 1);
    }
    // proj-mode: int64 iff all odd 32-bit words are zero
    if (t < 128) { if (pj[2 * t + 1] != 0) atomicAdd(&s_oddnz, 1); }
    // mask-mode from first 512 bytes
    for (int i = t; i < 512; i += 256) {
        unsigned char v = ((const unsigned char*)mbv)[i];
        if (v > 1) atomicAdd(&s_non01, 1);
        if ((i & 3) && v) atomicAdd(&s_off4, 1);
        if (((i & 3) < 2) && v) atomicAdd(&s_low2, 1);
    }
    __syncthreads();
    int f32m = (s_insane > 32) ? 1 : 0;
    if (t == 0) {
        scal[0] = -1;                       // init for atomicMax
        scal[2] = f32m;
        scal[3] = (s_oddnz == 0) ? 1 : 0;
        int mm;
        if (s_non01 == 0) mm = (s_off4 > 8) ? 0 : 1;       // u8 vs i32
        else              mm = (s_low2 > 0) ? 2 : 1;       // bf16 vs f32(i32 accessor ok)
        scal[4] = mm;
    }
    // convert W,b to f32 (branch is block-uniform)
    if (f32m) {
        const float* W = (const float*)Wv; const float* b = (const float*)bv;
        for (int i = t; i < 256 * 64; i += 256) Wf[i] = W[i];
        bf[t] = b[t];
    } else {
        const __hip_bfloat16* W = (const __hip_bfloat16*)Wv;
        const __hip_bfloat16* b = (const __hip_bfloat16*)bv;
        for (int i = t; i < 256 * 64; i += 256) Wf[i] = __bfloat162float(W[i]);
        bf[t] = __bfloat162float(b[t]);
    }
}

__global__ void k_max(const int* __restrict__ proj, int* __restrict__ scal) {
    int mode = scal[3];
    int i = blockIdx.x * 256 + threadIdx.x;
    int v = (i < MAPC) ? proj_at(proj, mode, i) : -1;
    for (int o = 32; o; o >>= 1) v = max(v, __shfl_down(v, o, 64));
    if ((threadIdx.x & 63) == 0) atomicMax(scal, v);
}

__global__ void k_count(const void* __restrict__ mask, const int* __restrict__ scal,
                        int* __restrict__ cnt) {
    int mode = scal[4];
    int chunk = blockIdx.x, t = threadIdx.x;
    int c = 0;
    for (int i = 0; i < 4; ++i)
        c += mask_at(mask, mode, chunk * CHSZ + i * 256 + t);
    for (int o = 32; o; o >>= 1) c += __shfl_down(c, o, 64);
    __shared__ int ws4[4];
    if ((t & 63) == 0) ws4[t >> 6] = c;
    __syncthreads();
    if (t == 0) cnt[chunk] = ws4[0] + ws4[1] + ws4[2] + ws4[3];
}

// single block, 256 threads; exclusive-scans cnt[2048] in place, total -> scal[1]
__global__ void k_scan(int* __restrict__ cnt, int* __restrict__ scal) {
    __shared__ int part[256];
    int t = threadIdx.x;
    int base = t * 8;
    int loc[8];
    int s = 0;
    for (int i = 0; i < 8; ++i) { loc[i] = s; s += cnt[base + i]; }
    part[t] = s;
    __syncthreads();
    int mine = s;
    for (int off = 1; off < 256; off <<= 1) {
        int add = (t >= off) ? part[t - off] : 0;
        __syncthreads();
        part[t] += add;
        __syncthreads();
    }
    int incl = part[t];
    int excl = incl - mine;
    for (int i = 0; i < 8; ++i) cnt[base + i] = excl + loc[i];
    if (t == 255) scal[1] = incl;
}

// positions[slot] = pixel index, for slots < NPOS only (all referenced slots)
__global__ void k_positions(const void* __restrict__ mask,
                            const int* __restrict__ cpre,
                            const int* __restrict__ scal,
                            int* __restrict__ positions) {
    int mode = scal[4];
    int chunk = blockIdx.x, t = threadIdx.x, w = t >> 6, lane = t & 63;
    int inBase = cpre[chunk];
    int outBase = chunk * CHSZ - inBase;
    int nin = scal[1];
    __shared__ int wsum[4];
    __shared__ int s_run;
    if (t == 0) s_run = 0;
    __syncthreads();
    for (int pass = 0; pass < 4; ++pass) {
        int q = pass * 256 + t;
        int px = chunk * CHSZ + q;
        bool isin = mask_at(mask, mode, px) != 0;
        unsigned long long bal = __ballot(isin);
        int before = __popcll(bal & ((1ULL << lane) - 1ULL));
        int wcnt = __popcll(bal);
        if (lane == 0) wsum[w] = wcnt;
        __syncthreads();
        int woff = 0;
        for (int ww = 0; ww < w; ++ww) woff += wsum[ww];
        int run = s_run;
        int in_rank = run + woff + before;
        int slot = isin ? (inBase + in_rank) : (nin + outBase + (q - in_rank));
        if (slot < NPOS) positions[slot] = px;
        __syncthreads();
        if (t == 0) s_run = run + wsum[0] + wsum[1] + wsum[2] + wsum[3];
        __syncthreads();
    }
}

// feat [64][128][256] (bf16 or f32) -> featT [128][256][64] bf16, via LDS tile
__global__ void k_transpose(const void* __restrict__ feat,
                            const int* __restrict__ scal,
                            __hip_bfloat16* __restrict__ featT) {
    __shared__ ushort_t tile[64][65];
    int f32m = scal[2];
    int y = blockIdx.x >> 2;
    int xt = (blockIdx.x & 3) * 64;
    int t = threadIdx.x;
    ushort_t* fout = (ushort_t*)featT;
    int xl = t & 63, cq = t >> 6;
    if (f32m) {
        const float* fin = (const float*)feat;
        for (int i = 0; i < 16; ++i) {
            int c = cq * 16 + i;
            __hip_bfloat16 h = __float2bfloat16(fin[c * 32768 + y * 256 + xt + xl]);
            tile[c][xl] = *(ushort_t*)&h;
        }
    } else {
        const ushort_t* fin = (const ushort_t*)feat;
        for (int i = 0; i < 16; ++i) {
            int c = cq * 16 + i;
            tile[c][xl] = fin[c * 32768 + y * 256 + xt + xl];
        }
    }
    __syncthreads();
    int cl = t & 63, xq = t >> 6;
    for (int i = 0; i < 16; ++i) {
        int x = xq * 16 + i;
        fout[(y * 256 + xt + x) * 64 + cl] = tile[cl][x];
    }
}

__global__ __launch_bounds__(256) void k_main(
    const __hip_bfloat16* __restrict__ featT,
    const int* __restrict__ proj,
    const int* __restrict__ positions,
    const float* __restrict__ Wf,
    const float* __restrict__ bf,
    const int* __restrict__ scal,
    float* __restrict__ out_mem,   // [256][MAPC] f32
    float* __restrict__ out_obs)   // [MAPC] f32
{
    __shared__ float f_lds[64][65];
    __shared__ int s_pm[64];
    int t = threadIdx.x;
    int lane = t & 63;
    int w = t >> 6;
    int cellbase = blockIdx.x * 64;
    int thr = scal[0];
    int pmode = scal[3];

    // Phase A: per-cell metadata + observed-mask output
    if (t < 64) {
        int i = cellbase + t;
        int pm = -1;
        if (i < MAPC) {
            int pi = proj_at(proj, pmode, i);
            bool m = pi < thr;
            if (m) pm = positions[pi];
            out_obs[i] = m ? 1.0f : 0.0f;
        }
        s_pm[t] = pm;
    }
    __syncthreads();

    // Phase B: bilinear interp, 4 cells per pass (one per wave), lane = channel
    {
        int c = t & 63;
        int jq = t >> 6;
        for (int pass = 0; pass < 16; ++pass) {
            int j = pass * 4 + jq;
            int p = s_pm[j];
            float v = 0.0f;
            if (p >= 0) {
                int y = p >> 11, x = p & 2047;
                float fy = (float)y * (127.0f / 1023.0f);
                float fx = (float)x * (255.0f / 2047.0f);
                int y0 = (int)fy, x0 = (int)fx;
                float wy = fy - (float)y0, wx = fx - (float)x0;
                int y1 = min(y0 + 1, 127), x1 = min(x0 + 1, 255);
                const __hip_bfloat16* b00 = featT + (y0 * 256 + x0) * 64;
                const __hip_bfloat16* b01 = featT + (y0 * 256 + x1) * 64;
                const __hip_bfloat16* b10 = featT + (y1 * 256 + x0) * 64;
                const __hip_bfloat16* b11 = featT + (y1 * 256 + x1) * 64;
                float f00 = __bfloat162float(b00[c]);
                float f01 = __bfloat162float(b01[c]);
                float f10 = __bfloat162float(b10[c]);
                float f11 = __bfloat162float(b11[c]);
                float top = f00 + wx * (f01 - f00);
                float bot = f10 + wx * (f11 - f10);
                v = top + wy * (bot - top);
            }
            f_lds[j][c] = v;
        }
    }
    __syncthreads();

    // Phase C: lane = cell; pull this cell's 64 channels into registers
    float fr[64];
    #pragma unroll
    for (int cc = 0; cc < 64; ++cc) fr[cc] = f_lds[lane][cc];

    int pm_l = s_pm[lane];
    int cell = cellbase + lane;
    bool valid = cell < MAPC;
    int kbase = __builtin_amdgcn_readfirstlane(w) * 64;   // force SGPR k-path

    // Phase D: wave w computes output channels [kbase, kbase+64)
    for (int kk = 0; kk < 64; kk += 2) {
        int k0 = kbase + kk;
        const float* w0 = Wf + k0 * 64;
        const float* w1 = w0 + 64;
        float a0 = 0.f, a1 = 0.f, a2 = 0.f, a3 = 0.f;
        #pragma unroll
        for (int cc = 0; cc < 64; cc += 2) {
            a0 += w0[cc]     * fr[cc];
            a1 += w0[cc + 1] * fr[cc + 1];
            a2 += w1[cc]     * fr[cc];
            a3 += w1[cc + 1] * fr[cc + 1];
        }
        float r0 = bf[k0] + a0 + a1;
        float r1 = bf[k0 + 1] + a2 + a3;
        if (pm_l < 0) { r0 = 0.f; r1 = 0.f; }
        if (valid) {
            out_mem[k0 * MAPC + cell]       = r0;
            out_mem[(k0 + 1) * MAPC + cell] = r1;
        }
    }
}

extern "C" void kernel_launch(void* const* d_in, const int* in_sizes, int n_in,
                              void* d_out, int out_size, void* d_ws, size_t ws_size,
                              hipStream_t stream) {
    const void* features = d_in[0];               // [64][128][256] f32 (or bf16)
    const int* proj = (const int*)d_in[1];        // [250000] i32 or i64
    const void* mask = d_in[2];                   // [1024*2048] bool as u8/i32/bf16/f32
    const void* W = d_in[3];                      // [256][64]
    const void* b = d_in[4];                      // [256]

    char* ws = (char*)d_ws;
    int* scal = (int*)(ws + OFF_SCAL);
    int* cnt = (int*)(ws + OFF_CNT);
    int* positions = (int*)(ws + OFF_POS);
    __hip_bfloat16* featT = (__hip_bfloat16*)(ws + OFF_FEATT);
    float* Wf = (float*)(ws + OFF_WF);
    float* bf = (float*)(ws + OFF_BF);

    float* out_mem = (float*)d_out;
    float* out_obs = out_mem + 256 * MAPC;

    hipLaunchKernelGGL(k_detect, dim3(1), dim3(256), 0, stream,
                       features, proj, mask, W, b, Wf, bf, scal);
    hipLaunchKernelGGL(k_max, dim3((MAPC + 255) / 256), dim3(256), 0, stream, proj, scal);
    hipLaunchKernelGGL(k_count, dim3(NCH), dim3(256), 0, stream, mask, scal, cnt);
    hipLaunchKernelGGL(k_scan, dim3(1), dim3(256), 0, stream, cnt, scal);
    hipLaunchKernelGGL(k_positions, dim3(NCH), dim3(256), 0, stream, mask, cnt, scal, positions);
    hipLaunchKernelGGL(k_transpose, dim3(512), dim3(256), 0, stream, features, scal, featT);
    hipLaunchKernelGGL(k_main, dim3((MAPC + 63) / 64), dim3(256), 0, stream,
                       featT, proj, positions, Wf, bf, scal, out_mem, out_obs);
}

// Round 4
// 387.110 us; speedup vs baseline: 1.2418x; 1.2418x over previous
//
#include <hip/hip_runtime.h>
#include <hip/hip_bf16.h>

typedef unsigned short ushort_t;
typedef unsigned int uint_t;
typedef __attribute__((ext_vector_type(8))) short short8;
typedef __attribute__((ext_vector_type(4))) float floatx4;

#define MAPC 250000
#define NCH 2048          // chunks for mask scan
#define CHSZ 1024         // pixels per chunk
#define NPOS 500000       // only slots < 500000 are ever referenced (proj < 500000)

// ws layout (bytes) — total 6,244,480
#define OFF_SCAL   0          // int[8]: [0]=max(proj) [1]=n_inliers [2]=f32mode [3]=projmode [4]=maskmode
#define OFF_CNT    1024       // int[2048]
#define OFF_POS    16384      // int[NPOS]  (2 MB)
#define OFF_FEATT  2016384    // bf16[128*256*64] (4 MB), layout [y][x][c]
#define OFF_WH     6210688    // bf16[256*64] (32 KB)
#define OFF_BF     6243456    // float[256]

__device__ inline int mask_at(const void* m, int mode, int px) {
    if (mode == 0) return ((const unsigned char*)m)[px] != 0;   // bool as u8
    if (mode == 2) return ((const ushort_t*)m)[px] != 0;        // bool as bf16
    return ((const int*)m)[px] != 0;                            // bool as i32 / f32
}

__device__ inline int proj_at(const int* p, int mode, int i) {
    return mode ? p[2 * i] : p[i];                              // int64 low word / int32
}

// Detect input layouts + convert W->bf16, b->f32. One block, 256 threads.
__global__ void k_detect(const void* feats, const int* pj, const void* mbv,
                         const void* Wv, const void* bv,
                         ushort_t* __restrict__ Wh, float* __restrict__ bfl,
                         int* __restrict__ scal) {
    __shared__ int s_insane, s_oddnz, s_non01, s_off4, s_low2;
    int t = threadIdx.x;
    if (t == 0) { s_insane = 0; s_oddnz = 0; s_non01 = 0; s_off4 = 0; s_low2 = 0; }
    __syncthreads();
    {
        ushort_t u = ((const ushort_t*)feats)[2 * t];
        int e = (u >> 7) & 0xFF;
        if (e < 0x66 || e > 0x8E) atomicAdd(&s_insane, 1);
    }
    if (t < 128) { if (pj[2 * t + 1] != 0) atomicAdd(&s_oddnz, 1); }
    for (int i = t; i < 512; i += 256) {
        unsigned char v = ((const unsigned char*)mbv)[i];
        if (v > 1) atomicAdd(&s_non01, 1);
        if ((i & 3) && v) atomicAdd(&s_off4, 1);
        if (((i & 3) < 2) && v) atomicAdd(&s_low2, 1);
    }
    __syncthreads();
    int f32m = (s_insane > 32) ? 1 : 0;
    if (t == 0) {
        scal[0] = -1;
        scal[2] = f32m;
        scal[3] = (s_oddnz == 0) ? 1 : 0;
        int mm;
        if (s_non01 == 0) mm = (s_off4 > 8) ? 0 : 1;       // u8 vs i32
        else              mm = (s_low2 > 0) ? 2 : 1;       // bf16 vs f32
        scal[4] = mm;
    }
    if (f32m) {
        const float* W = (const float*)Wv; const float* b = (const float*)bv;
        for (int i = t; i < 256 * 64; i += 256) {
            __hip_bfloat16 h = __float2bfloat16(W[i]);
            Wh[i] = *(ushort_t*)&h;
        }
        bfl[t] = b[t];
    } else {
        const ushort_t* W = (const ushort_t*)Wv;
        const __hip_bfloat16* b = (const __hip_bfloat16*)bv;
        for (int i = t; i < 256 * 64; i += 256) Wh[i] = W[i];
        bfl[t] = __bfloat162float(b[t]);
    }
}

__global__ void k_max(const int* __restrict__ proj, int* __restrict__ scal) {
    int mode = scal[3];
    int i = blockIdx.x * 256 + threadIdx.x;
    int v = (i < MAPC) ? proj_at(proj, mode, i) : -1;
    for (int o = 32; o; o >>= 1) v = max(v, __shfl_down(v, o, 64));
    if ((threadIdx.x & 63) == 0) atomicMax(scal, v);
}

__global__ void k_count(const void* __restrict__ mask, const int* __restrict__ scal,
                        int* __restrict__ cnt) {
    int mode = scal[4];
    int chunk = blockIdx.x, t = threadIdx.x;
    int c = 0;
    for (int i = 0; i < 4; ++i)
        c += mask_at(mask, mode, chunk * CHSZ + i * 256 + t);
    for (int o = 32; o; o >>= 1) c += __shfl_down(c, o, 64);
    __shared__ int ws4[4];
    if ((t & 63) == 0) ws4[t >> 6] = c;
    __syncthreads();
    if (t == 0) cnt[chunk] = ws4[0] + ws4[1] + ws4[2] + ws4[3];
}

__global__ void k_scan(int* __restrict__ cnt, int* __restrict__ scal) {
    __shared__ int part[256];
    int t = threadIdx.x;
    int base = t * 8;
    int loc[8];
    int s = 0;
    for (int i = 0; i < 8; ++i) { loc[i] = s; s += cnt[base + i]; }
    part[t] = s;
    __syncthreads();
    int mine = s;
    for (int off = 1; off < 256; off <<= 1) {
        int add = (t >= off) ? part[t - off] : 0;
        __syncthreads();
        part[t] += add;
        __syncthreads();
    }
    int incl = part[t];
    int excl = incl - mine;
    for (int i = 0; i < 8; ++i) cnt[base + i] = excl + loc[i];
    if (t == 255) scal[1] = incl;
}

__global__ void k_positions(const void* __restrict__ mask,
                            const int* __restrict__ cpre,
                            const int* __restrict__ scal,
                            int* __restrict__ positions) {
    int mode = scal[4];
    int chunk = blockIdx.x, t = threadIdx.x, w = t >> 6, lane = t & 63;
    int inBase = cpre[chunk];
    int outBase = chunk * CHSZ - inBase;
    int nin = scal[1];
    __shared__ int wsum[4];
    __shared__ int s_run;
    if (t == 0) s_run = 0;
    __syncthreads();
    for (int pass = 0; pass < 4; ++pass) {
        int q = pass * 256 + t;
        int px = chunk * CHSZ + q;
        bool isin = mask_at(mask, mode, px) != 0;
        unsigned long long bal = __ballot(isin);
        int before = __popcll(bal & ((1ULL << lane) - 1ULL));
        int wcnt = __popcll(bal);
        if (lane == 0) wsum[w] = wcnt;
        __syncthreads();
        int woff = 0;
        for (int ww = 0; ww < w; ++ww) woff += wsum[ww];
        int run = s_run;
        int in_rank = run + woff + before;
        int slot = isin ? (inBase + in_rank) : (nin + outBase + (q - in_rank));
        if (slot < NPOS) positions[slot] = px;
        __syncthreads();
        if (t == 0) s_run = run + wsum[0] + wsum[1] + wsum[2] + wsum[3];
        __syncthreads();
    }
}

// feat [64][128][256] (bf16 or f32) -> featT [128][256][64] bf16, via LDS tile
__global__ void k_transpose(const void* __restrict__ feat,
                            const int* __restrict__ scal,
                            __hip_bfloat16* __restrict__ featT) {
    __shared__ ushort_t tile[64][65];
    int f32m = scal[2];
    int y = blockIdx.x >> 2;
    int xt = (blockIdx.x & 3) * 64;
    int t = threadIdx.x;
    ushort_t* fout = (ushort_t*)featT;
    int xl = t & 63, cq = t >> 6;
    if (f32m) {
        const float* fin = (const float*)feat;
        for (int i = 0; i < 16; ++i) {
            int c = cq * 16 + i;
            __hip_bfloat16 h = __float2bfloat16(fin[c * 32768 + y * 256 + xt + xl]);
            tile[c][xl] = *(ushort_t*)&h;
        }
    } else {
        const ushort_t* fin = (const ushort_t*)feat;
        for (int i = 0; i < 16; ++i) {
            int c = cq * 16 + i;
            tile[c][xl] = fin[c * 32768 + y * 256 + xt + xl];
        }
    }
    __syncthreads();
    int cl = t & 63, xq = t >> 6;
    for (int i = 0; i < 16; ++i) {
        int x = xq * 16 + i;
        fout[(y * 256 + xt + x) * 64 + cl] = tile[cl][x];
    }
}

// MFMA main: block = 64 cells x 256 out-channels. Wave w: channels [64w,64w+64).
// A = W[channel][c] (m=channel), B = interp[cell][c] (n=cell), K=c=64.
__global__ __launch_bounds__(256) void k_main(
    const __hip_bfloat16* __restrict__ featT,
    const int* __restrict__ proj,
    const int* __restrict__ positions,
    const ushort_t* __restrict__ Wh,     // bf16 [256][64]
    const float* __restrict__ bfl,       // f32 [256]
    const int* __restrict__ scal,
    float* __restrict__ out_mem,         // [256][MAPC] f32
    float* __restrict__ out_obs)         // [MAPC] f32
{
    __shared__ ushort_t B_lds[64 * 72];  // [cell][c], pad 72 -> 2-way bank alias (free)
    __shared__ int s_pm[64];
    __shared__ float s_bias[256];
    int t = threadIdx.x;
    int r15 = t & 15;
    int quad = (t >> 4) & 3;
    int w = t >> 6;
    int cellbase = blockIdx.x * 64;
    int thr = scal[0];
    int pmode = scal[3];

    s_bias[t] = bfl[t];

    // Phase A: per-cell gather index + observed-mask output
    if (t < 64) {
        int i = cellbase + t;
        int pm = -1;
        if (i < MAPC) {
            int pi = proj_at(proj, pmode, i);
            bool m = pi < thr;
            if (m) pm = positions[pi];
            out_obs[i] = m ? 1.0f : 0.0f;
        }
        s_pm[t] = pm;
    }
    __syncthreads();

    // Phase B: bilinear interp, 2 channels/thread, 8 cells per pass -> bf16x2 LDS
    {
        int cp = t & 31;            // channel pair index: c = 2*cp
        int jq = t >> 5;            // 0..7
        for (int pass = 0; pass < 8; ++pass) {
            int j = pass * 8 + jq;
            int p = s_pm[j];
            float v0 = 0.0f, v1 = 0.0f;
            if (p >= 0) {
                int y = p >> 11, x = p & 2047;
                float fy = (float)y * (127.0f / 1023.0f);
                float fx = (float)x * (255.0f / 2047.0f);
                int y0 = (int)fy, x0 = (int)fx;
                float wy = fy - (float)y0, wx = fx - (float)x0;
                int y1 = min(y0 + 1, 127), x1 = min(x0 + 1, 255);
                const uint_t* p00 = (const uint_t*)(featT + (y0 * 256 + x0) * 64);
                const uint_t* p01 = (const uint_t*)(featT + (y0 * 256 + x1) * 64);
                const uint_t* p10 = (const uint_t*)(featT + (y1 * 256 + x0) * 64);
                const uint_t* p11 = (const uint_t*)(featT + (y1 * 256 + x1) * 64);
                uint_t u00 = p00[cp], u01 = p01[cp], u10 = p10[cp], u11 = p11[cp];
                float f00l = __uint_as_float(u00 << 16), f00h = __uint_as_float(u00 & 0xFFFF0000u);
                float f01l = __uint_as_float(u01 << 16), f01h = __uint_as_float(u01 & 0xFFFF0000u);
                float f10l = __uint_as_float(u10 << 16), f10h = __uint_as_float(u10 & 0xFFFF0000u);
                float f11l = __uint_as_float(u11 << 16), f11h = __uint_as_float(u11 & 0xFFFF0000u);
                float topl = f00l + wx * (f01l - f00l);
                float botl = f10l + wx * (f11l - f10l);
                v0 = topl + wy * (botl - topl);
                float toph = f00h + wx * (f01h - f00h);
                float both = f10h + wx * (f11h - f10h);
                v1 = toph + wy * (both - toph);
            }
            __hip_bfloat16 h0 = __float2bfloat16(v0);
            __hip_bfloat16 h1 = __float2bfloat16(v1);
            uint_t packed = ((uint_t)(*(ushort_t*)&h1) << 16) | (uint_t)(*(ushort_t*)&h0);
            *(uint_t*)&B_lds[j * 72 + cp * 2] = packed;
        }
    }
    __syncthreads();

    // Phase C: W fragments (A-operand): A[m=r15][k=quad*8+j]
    int chb = __builtin_amdgcn_readfirstlane(w) * 64;
    short8 afr[4][2];
    #pragma unroll
    for (int mt = 0; mt < 4; ++mt)
        #pragma unroll
        for (int ks = 0; ks < 2; ++ks)
            afr[mt][ks] = *(const short8*)(Wh + (chb + mt * 16 + r15) * 64 + ks * 32 + quad * 8);

    floatx4 acc[4][4];
    #pragma unroll
    for (int mt = 0; mt < 4; ++mt)
        #pragma unroll
        for (int nt = 0; nt < 4; ++nt)
            acc[mt][nt] = (floatx4){0.f, 0.f, 0.f, 0.f};

    // Phase D: MFMA. B-operand: B[k=quad*8+j][n=r15] = B_lds[cell][c]
    #pragma unroll
    for (int nt = 0; nt < 4; ++nt) {
        short8 b0 = *(const short8*)&B_lds[(nt * 16 + r15) * 72 + quad * 8];
        short8 b1 = *(const short8*)&B_lds[(nt * 16 + r15) * 72 + 32 + quad * 8];
        #pragma unroll
        for (int mt = 0; mt < 4; ++mt) {
            acc[mt][nt] = __builtin_amdgcn_mfma_f32_16x16x32_bf16(afr[mt][0], b0, acc[mt][nt], 0, 0, 0);
            acc[mt][nt] = __builtin_amdgcn_mfma_f32_16x16x32_bf16(afr[mt][1], b1, acc[mt][nt], 0, 0, 0);
        }
    }

    // Epilogue: D[m=quad*4+reg][n=r15]; channel = chb+mt*16+quad*4+reg, cell = cellbase+nt*16+r15
    #pragma unroll
    for (int nt = 0; nt < 4; ++nt) {
        int cell = cellbase + nt * 16 + r15;
        bool ok = cell < MAPC;
        float z = (s_pm[nt * 16 + r15] < 0) ? 0.0f : 1.0f;
        #pragma unroll
        for (int mt = 0; mt < 4; ++mt) {
            int ch0 = chb + mt * 16 + quad * 4;
            #pragma unroll
            for (int reg = 0; reg < 4; ++reg) {
                float r = (acc[mt][nt][reg] + s_bias[ch0 + reg]) * z;
                if (ok) out_mem[(size_t)(ch0 + reg) * MAPC + cell] = r;
            }
        }
    }
}

extern "C" void kernel_launch(void* const* d_in, const int* in_sizes, int n_in,
                              void* d_out, int out_size, void* d_ws, size_t ws_size,
                              hipStream_t stream) {
    const void* features = d_in[0];               // [64][128][256] f32 (or bf16)
    const int* proj = (const int*)d_in[1];        // [250000] i32 or i64
    const void* mask = d_in[2];                   // [1024*2048] bool
    const void* W = d_in[3];                      // [256][64]
    const void* b = d_in[4];                      // [256]

    char* ws = (char*)d_ws;
    int* scal = (int*)(ws + OFF_SCAL);
    int* cnt = (int*)(ws + OFF_CNT);
    int* positions = (int*)(ws + OFF_POS);
    __hip_bfloat16* featT = (__hip_bfloat16*)(ws + OFF_FEATT);
    ushort_t* Wh = (ushort_t*)(ws + OFF_WH);
    float* bfl = (float*)(ws + OFF_BF);

    float* out_mem = (float*)d_out;
    float* out_obs = out_mem + (size_t)256 * MAPC;

    hipLaunchKernelGGL(k_detect, dim3(1), dim3(256), 0, stream,
                       features, proj, mask, W, b, Wh, bfl, scal);
    hipLaunchKernelGGL(k_max, dim3((MAPC + 255) / 256), dim3(256), 0, stream, proj, scal);
    hipLaunchKernelGGL(k_count, dim3(NCH), dim3(256), 0, stream, mask, scal, cnt);
    hipLaunchKernelGGL(k_scan, dim3(1), dim3(256), 0, stream, cnt, scal);
    hipLaunchKernelGGL(k_positions, dim3(NCH), dim3(256), 0, stream, mask, cnt, scal, positions);
    hipLaunchKernelGGL(k_transpose, dim3(512), dim3(256), 0, stream, features, scal, featT);
    hipLaunchKernelGGL(k_main, dim3((MAPC + 63) / 64), dim3(256), 0, stream,
                       featT, proj, positions, Wh, bfl, scal, out_mem, out_obs);
}